// Round 1
// 509.201 us; speedup vs baseline: 1.4231x; 1.4231x over previous
//
#include <hip/hip_runtime.h>
#include <stdint.h>

#define L_SEQ 2048
#define S_SEQ 2048
#define NB 2
#define EMB 1024
#define NH 16
#define DH 64
#define NC 32
#define MROWS 4096  // L*NB

typedef __bf16 bf16x8 __attribute__((ext_vector_type(8)));
typedef float f32x4 __attribute__((ext_vector_type(4)));

__device__ __forceinline__ float bf2f(unsigned short u) {
  return __builtin_bit_cast(float, (uint32_t)u << 16);
}
__device__ __forceinline__ unsigned short f2bf(float f) {
  uint32_t u = __builtin_bit_cast(uint32_t, f);
  return (unsigned short)((u + 0x7FFFu + ((u >> 16) & 1u)) >> 16);
}

// C = A @ B^T + bias. MFMA bf16, 128x128 tile (m93/m97-validated structure).
// A_BF16: 0 = A is f32 global (inline RNE convert), 1 = A is bf16 workspace.
// B always f32 global (inline convert). Out: f32 if outF, else bf16 outB.
template <int A_BF16>
__global__ void __launch_bounds__(256) gemm_bt_mfma(
    const void* __restrict__ Av, const float* __restrict__ B,
    const float* __restrict__ bias,
    float* __restrict__ outF, unsigned short* __restrict__ outB)
{
  __shared__ __align__(16) unsigned short As[128][32];  // unpadded 64B rows (b128-aligned)
  __shared__ __align__(16) unsigned short Bs[128][32];
  const int K = EMB;
  int tid = threadIdx.x;
  int m0 = blockIdx.y * 128, n0 = blockIdx.x * 128;
  int wave = tid >> 6, lane = tid & 63;
  int wm = (wave >> 1) * 64, wn = (wave & 1) * 64;

  f32x4 zero = {0.f, 0.f, 0.f, 0.f};
  f32x4 acc[4][4];
#pragma unroll
  for (int mi = 0; mi < 4; mi++)
#pragma unroll
    for (int ni = 0; ni < 4; ni++) acc[mi][ni] = zero;

  int fr = lane & 15, fk = (lane >> 4) * 8;

  for (int k0 = 0; k0 < K; k0 += 32) {
    __syncthreads();
#pragma unroll
    for (int it = 0; it < 2; it++) {
      int ch = tid + it * 256;          // 512 chunks of 8 elems per tile
      int row = ch >> 2, kk = (ch & 3) * 8;
      if (A_BF16) {
        const unsigned short* ap = (const unsigned short*)Av + (size_t)(m0 + row) * K + k0 + kk;
        *(uint4*)(&As[row][kk]) = *(const uint4*)ap;
      } else {
        const float* ap = (const float*)Av + (size_t)(m0 + row) * K + k0 + kk;
        float4 a0 = *(const float4*)ap, a1 = *(const float4*)(ap + 4);
        uint4 u;
        u.x = (uint32_t)f2bf(a0.x) | ((uint32_t)f2bf(a0.y) << 16);
        u.y = (uint32_t)f2bf(a0.z) | ((uint32_t)f2bf(a0.w) << 16);
        u.z = (uint32_t)f2bf(a1.x) | ((uint32_t)f2bf(a1.y) << 16);
        u.w = (uint32_t)f2bf(a1.z) | ((uint32_t)f2bf(a1.w) << 16);
        *(uint4*)(&As[row][kk]) = u;
      }
      {
        const float* bp = B + (size_t)(n0 + row) * K + k0 + kk;
        float4 b0 = *(const float4*)bp, b1 = *(const float4*)(bp + 4);
        uint4 u;
        u.x = (uint32_t)f2bf(b0.x) | ((uint32_t)f2bf(b0.y) << 16);
        u.y = (uint32_t)f2bf(b0.z) | ((uint32_t)f2bf(b0.w) << 16);
        u.z = (uint32_t)f2bf(b1.x) | ((uint32_t)f2bf(b1.y) << 16);
        u.w = (uint32_t)f2bf(b1.z) | ((uint32_t)f2bf(b1.w) << 16);
        *(uint4*)(&Bs[row][kk]) = u;
      }
    }
    __syncthreads();
    bf16x8 af[4], bfr[4];
#pragma unroll
    for (int i = 0; i < 4; i++) af[i] = *(const bf16x8*)(&As[wm + i * 16 + fr][fk]);
#pragma unroll
    for (int i = 0; i < 4; i++) bfr[i] = *(const bf16x8*)(&Bs[wn + i * 16 + fr][fk]);
#pragma unroll
    for (int mi = 0; mi < 4; mi++)
#pragma unroll
      for (int ni = 0; ni < 4; ni++)
        acc[mi][ni] = __builtin_amdgcn_mfma_f32_16x16x32_bf16(af[mi], bfr[ni], acc[mi][ni], 0, 0, 0);
  }

#pragma unroll
  for (int ni = 0; ni < 4; ni++) {
    int col = n0 + wn + ni * 16 + (lane & 15);
    float bv = bias[col];
#pragma unroll
    for (int mi = 0; mi < 4; mi++) {
#pragma unroll
      for (int r = 0; r < 4; r++) {
        int row = m0 + wm + mi * 16 + (lane >> 4) * 4 + r;
        float v = acc[mi][ni][r] + bv;
        if (outF) outF[(size_t)row * EMB + col] = v;
        else outB[(size_t)row * EMB + col] = f2bf(v);
      }
    }
  }
}

// Wc[c][k] = sum_e W[e][k]*cent[c][e]; bd[c] = sum_e bias[e]*cent[c][e]; f64 (exact reassociation:
// (x@W^T+b)·cent_c = sum_k x_k*Wc[c][k] + bd[c]). Inputs f32.
__global__ void __launch_bounds__(256) prep_wc_kernel(
    const float* __restrict__ W, const float* __restrict__ bias,
    const float* __restrict__ cent,
    double* __restrict__ Wc, double* __restrict__ bd)
{
  int k = blockIdx.x;
  int tid = threadIdx.x;
  int c = tid & 31, g = tid >> 5;
  __shared__ double red[8][32];
  double s = 0.0;
  for (int e = g * 128; e < (g + 1) * 128; e++)
    s += (double)W[(size_t)e * EMB + k] * (double)cent[(size_t)c * EMB + e];
  red[g][c] = s;
  __syncthreads();
  if (tid < 32) {
    double t = 0.0;
#pragma unroll
    for (int gg = 0; gg < 8; gg++) t += red[gg][tid];
    Wc[(size_t)tid * EMB + k] = t;
  }
  if (k == 0) {
    __syncthreads();
    double s2 = 0.0;
    for (int e = g * 128; e < (g + 1) * 128; e++)
      s2 += (double)bias[e] * (double)cent[(size_t)c * EMB + e];
    red[g][c] = s2;
    __syncthreads();
    if (tid < 32) {
      double t = 0.0;
#pragma unroll
      for (int gg = 0; gg < 8; gg++) t += red[gg][tid];
      bd[tid] = t;
    }
  }
}

// Assignment from RAW f32 input rows via Wc: f64 dots, first-max argmax. (Bit-agreed with
// projected-cosine assignment in R3-R6 cross-validation.)
__global__ void __launch_bounds__(256) assign2_kernel(
    const float* __restrict__ X, const double* __restrict__ Wc,
    const double* __restrict__ bd,
    int* __restrict__ cluster, int* __restrict__ count)
{
  int r0 = blockIdx.x * 4;
  int tid = threadIdx.x;
  int c = tid & 31, seg = tid >> 5;
  __shared__ double red[4][32][8];
  __shared__ double dots[4][32];

  const double* wp = Wc + (size_t)c * EMB + seg * 128;
  double acc4[4] = {0.0, 0.0, 0.0, 0.0};
  for (int i = 0; i < 128; i += 2) {
    double2 w2 = *(const double2*)(wp + i);
#pragma unroll
    for (int r = 0; r < 4; r++) {
      float2 xu = *(const float2*)(X + (size_t)(r0 + r) * EMB + seg * 128 + i);
      acc4[r] += (double)xu.x * w2.x + (double)xu.y * w2.y;
    }
  }
#pragma unroll
  for (int r = 0; r < 4; r++) red[r][c][seg] = acc4[r];
  __syncthreads();
  if (tid < 128) {
    int r = tid >> 5, cc = tid & 31;
    double t = 0.0;
#pragma unroll
    for (int s = 0; s < 8; s++) t += red[r][cc][s];
    dots[r][cc] = t + bd[cc];
  }
  __syncthreads();
  if (tid < 4) {
    double best = dots[tid][0]; int bc = 0;
    for (int cc = 1; cc < NC; cc++)
      if (dots[tid][cc] > best) { best = dots[tid][cc]; bc = cc; }   // first-max
    int row = r0 + tid;
    cluster[row] = bc;
    atomicAdd(&count[(row & 1) * NC + bc], 1);
  }
}

__global__ void scan_kernel(const int* __restrict__ qcount, const int* __restrict__ kcount,
                            int* __restrict__ qoff, int* __restrict__ koff)
{
  int tid = threadIdx.x;
  if (tid < 2) {
    int run = 0;
    for (int c = 0; c < NC; c++) { qoff[tid * NC + c] = run; run += qcount[tid * NC + c]; }
  } else if (tid < 4) {
    int n = tid - 2, run = 0;
    for (int c = 0; c < NC; c++) { koff[n * NC + c] = run; run += kcount[n * NC + c]; }
  }
}

__global__ void __launch_bounds__(256) scatter_kernel(
    const int* __restrict__ q_cluster, const int* __restrict__ k_cluster,
    const int* __restrict__ qoff, const int* __restrict__ koff,
    int* __restrict__ qfill, int* __restrict__ kfill,
    int* __restrict__ qlist, int* __restrict__ klist)
{
  int id = blockIdx.x * 256 + threadIdx.x;
  if (id < MROWS) {
    int row = id, n = row & 1, l = row >> 1, c = q_cluster[row];
    int pos = atomicAdd(&qfill[n * NC + c], 1);
    qlist[n * L_SEQ + qoff[n * NC + c] + pos] = l;
  } else {
    int row = id - MROWS, n = row & 1, s = row >> 1, c = k_cluster[row];
    int pos = atomicAdd(&kfill[n * NC + c], 1);
    klist[n * S_SEQ + koff[n * NC + c] + pos] = s;
  }
}

// Bucketed attention, MFMA flash-style. Block=(cluster,head,batch), 4 waves, 16 queries/wave,
// 64-key chunks with online softmax. Swapped operands keep softmax per-lane-uniform:
//   S^T = mfma(A=K, B=Q)    -> D[row=key=4g+r][col=q=lane&15]
//   O^T = mfma(A=V^T, B=P^T)-> D[row=d  =4g+r][col=q=lane&15]
// so running max / lsum / rescale are one scalar per lane (reduce = shfl_xor 16,32).
// P^T relayout through wave-private LDS: C-frag writes 4 consecutive keys (ds_write_b64),
// B-frag reads 8 consecutive keys (ds_read_b128). All LDS tiles row-XOR-swizzled
// (elem_col ^= (row&7)<<3, i.e. byte ^= (row&7)<<4) to kill the 16-way b128 bank conflict.
// Frag addressing pattern identical to gemm_bt_mfma above (harness-validated layout).
__global__ void __launch_bounds__(256) attn_bucket(
    const unsigned short* __restrict__ Qb, const unsigned short* __restrict__ Kb,
    const unsigned short* __restrict__ Vb,
    const int* __restrict__ qcount, const int* __restrict__ qoff, const int* __restrict__ qlist,
    const int* __restrict__ kcount, const int* __restrict__ koff, const int* __restrict__ klist,
    unsigned short* __restrict__ ctx)
{
  int c = blockIdx.x, h = blockIdx.y, n = blockIdx.z;
  int Sc = kcount[n * NC + c], k0base = koff[n * NC + c];
  int Lc = qcount[n * NC + c], q0 = qoff[n * NC + c];
  int tid = threadIdx.x, wave = tid >> 6, lane = tid & 63;
  int lg = lane >> 4, lq = lane & 15;

  __shared__ __align__(16) unsigned short Ks[64][64];    // [key][d], row-swizzled
  __shared__ __align__(16) unsigned short Vts[64][64];   // [d][key], row-swizzled
  __shared__ __align__(16) unsigned short Pts[4][16][64]; // per-wave [q][key], row-swizzled
  __shared__ int rb[64];                                  // gathered K/V row base offsets

  if (Sc == 0) {   // no keys: ref softmax would be NaN; R9 proved this never occurs. Write 0.
    for (int qi = wave; qi < Lc; qi += 4) {
      int l = qlist[n * L_SEQ + q0 + qi];
      ctx[((size_t)(n * L_SEQ + l)) * EMB + h * DH + lane] = 0;
    }
    return;
  }

  const int* kl = klist + n * S_SEQ + k0base;
  const int* ql = qlist + n * L_SEQ + q0;
  f32x4 zero = {0.f, 0.f, 0.f, 0.f};

  for (int qb = 0; qb < Lc; qb += 64) {           // uniform trip count across waves
    int qq = qb + wave * 16 + lq;
    int qqc = qq < Lc ? qq : Lc - 1;              // clamp: padded lanes duplicate last query
    int lrow = ql[qqc];
    const unsigned short* qp = Qb + ((size_t)(lrow * NB + n)) * EMB + h * DH;
    bf16x8 qf0 = *(const bf16x8*)(qp + lg * 8);          // B=Q frag: col=q, k=d 0..31
    bf16x8 qf1 = *(const bf16x8*)(qp + 32 + lg * 8);     //                  d 32..63

    f32x4 acc[4];                                  // O^T: 4 d-tiles, col=q per lane
#pragma unroll
    for (int di = 0; di < 4; di++) acc[di] = zero;
    float m = -3.0e38f, lsum = 0.f;

    for (int kc = 0; kc < Sc; kc += 64) {
      __syncthreads();                             // prev chunk compute done
      if (tid < 64) {
        int jj = kc + tid; if (jj >= Sc) jj = Sc - 1;   // clamp-pad: valid finite rows
        rb[tid] = (kl[jj] * NB + n) * EMB + h * DH;
      }
      __syncthreads();                             // rb ready
#pragma unroll
      for (int it = 0; it < 2; it++) {
        int p = it * 256 + tid;                    // 512 pieces
        {                                          // K: [key][d] 16B pieces
          int row = p >> 3, seg = p & 7;
          uint4 u = *(const uint4*)(Kb + rb[row] + seg * 8);
          *(uint4*)(&Ks[row][(seg * 8) ^ ((row & 7) << 3)]) = u;
        }
        {                                          // V^T: gather column d, 8 keys
          int d = p & 63, kg = p >> 6;
          unsigned short v0 = Vb[rb[kg * 8 + 0] + d], v1 = Vb[rb[kg * 8 + 1] + d];
          unsigned short v2 = Vb[rb[kg * 8 + 2] + d], v3 = Vb[rb[kg * 8 + 3] + d];
          unsigned short v4 = Vb[rb[kg * 8 + 4] + d], v5 = Vb[rb[kg * 8 + 5] + d];
          unsigned short v6 = Vb[rb[kg * 8 + 6] + d], v7 = Vb[rb[kg * 8 + 7] + d];
          uint4 u;
          u.x = (uint32_t)v0 | ((uint32_t)v1 << 16);
          u.y = (uint32_t)v2 | ((uint32_t)v3 << 16);
          u.z = (uint32_t)v4 | ((uint32_t)v5 << 16);
          u.w = (uint32_t)v6 | ((uint32_t)v7 << 16);
          *(uint4*)(&Vts[d][(kg * 8) ^ ((d & 7) << 3)]) = u;
        }
      }
      __syncthreads();                             // K/V^T staged

      // S^T = K @ Q^T : 4 key-tiles x 2 d-steps
      f32x4 st[4];
#pragma unroll
      for (int ni = 0; ni < 4; ni++) st[ni] = zero;
#pragma unroll
      for (int ni = 0; ni < 4; ni++) {
        int row = ni * 16 + lq;
        bf16x8 kf0 = *(const bf16x8*)(&Ks[row][(lg * 8) ^ ((row & 7) << 3)]);
        bf16x8 kf1 = *(const bf16x8*)(&Ks[row][(32 + lg * 8) ^ ((row & 7) << 3)]);
        st[ni] = __builtin_amdgcn_mfma_f32_16x16x32_bf16(kf0, qf0, st[ni], 0, 0, 0);
        st[ni] = __builtin_amdgcn_mfma_f32_16x16x32_bf16(kf1, qf1, st[ni], 0, 0, 0);
      }

      // online softmax (per-lane scalar state; clamp-padded keys duplicate valid
      // scores so they cannot change the max; they are zeroed in p below)
      int lim = Sc - kc;
      float cm = -3.0e38f;
#pragma unroll
      for (int ni = 0; ni < 4; ni++) {
        st[ni] = st[ni] * 0.125f;                  // 1/sqrt(64)
#pragma unroll
        for (int r = 0; r < 4; r++) cm = fmaxf(cm, st[ni][r]);
      }
      cm = fmaxf(cm, __shfl_xor(cm, 16, 64));
      cm = fmaxf(cm, __shfl_xor(cm, 32, 64));
      float mn = fmaxf(m, cm);
      float fac = __expf(m - mn);
      m = mn;
      lsum *= fac;
#pragma unroll
      for (int di = 0; di < 4; di++) acc[di] = acc[di] * fac;

      // P^T -> LDS (bf16); lsum over ROUNDED p so O stays a true weighted average
#pragma unroll
      for (int ni = 0; ni < 4; ni++) {
        int kloc = ni * 16 + lg * 4;
        float p0 = (kloc + 0 < lim) ? __expf(st[ni][0] - mn) : 0.f;
        float p1 = (kloc + 1 < lim) ? __expf(st[ni][1] - mn) : 0.f;
        float p2 = (kloc + 2 < lim) ? __expf(st[ni][2] - mn) : 0.f;
        float p3 = (kloc + 3 < lim) ? __expf(st[ni][3] - mn) : 0.f;
        unsigned short b0 = f2bf(p0), b1 = f2bf(p1), b2 = f2bf(p2), b3 = f2bf(p3);
        lsum += bf2f(b0) + bf2f(b1) + bf2f(b2) + bf2f(b3);
        ushort4 u4; u4.x = b0; u4.y = b1; u4.z = b2; u4.w = b3;
        *(ushort4*)(&Pts[wave][lq][kloc ^ ((lq & 7) << 3)]) = u4;
      }

      // O^T += V^T @ P^T : 4 d-tiles x 2 key-steps
#pragma unroll
      for (int ks = 0; ks < 2; ks++) {
        bf16x8 pf = *(const bf16x8*)(&Pts[wave][lq][(ks * 32 + lg * 8) ^ ((lq & 7) << 3)]);
#pragma unroll
        for (int di = 0; di < 4; di++) {
          int row = di * 16 + lq;
          bf16x8 vf = *(const bf16x8*)(&Vts[row][(ks * 32 + lg * 8) ^ ((row & 7) << 3)]);
          acc[di] = __builtin_amdgcn_mfma_f32_16x16x32_bf16(vf, pf, acc[di], 0, 0, 0);
        }
      }
    }

    lsum += __shfl_xor(lsum, 16, 64);
    lsum += __shfl_xor(lsum, 32, 64);
    float rinv = 1.f / lsum;
    if (qq < Lc) {                                 // padded duplicates skip the store
      unsigned short* op = ctx + ((size_t)(n * L_SEQ + lrow)) * EMB + h * DH;
#pragma unroll
      for (int di = 0; di < 4; di++) {
        ushort4 o;
        o.x = f2bf(acc[di][0] * rinv);
        o.y = f2bf(acc[di][1] * rinv);
        o.z = f2bf(acc[di][2] * rinv);
        o.w = f2bf(acc[di][3] * rinv);
        *(ushort4*)(op + di * 16 + lg * 4) = o;    // d = di*16 + 4g + r, contiguous r
      }
    }
  }
}

// Residual + LayerNorm, f32 output. out row r = l*NB+n; proj row = n*L+l. (R9-validated.)
__global__ void __launch_bounds__(256) ln_kernel(
    const float* __restrict__ proj, const float* __restrict__ query,
    const float* __restrict__ gamma, const float* __restrict__ beta,
    float* __restrict__ out)
{
  int r = blockIdx.x;
  int l = r >> 1, n = r & 1;
  int tid = threadIdx.x, wave = tid >> 6, lane = tid & 63;
  float4 p = *(const float4*)(proj + ((size_t)(n * L_SEQ + l)) * EMB + tid * 4);
  float4 qu = *(const float4*)(query + (size_t)r * EMB + tid * 4);
  float res[4] = { p.x + qu.x, p.y + qu.y, p.z + qu.z, p.w + qu.w };
  float s1 = res[0] + res[1] + res[2] + res[3];
  float s2 = res[0] * res[0] + res[1] * res[1] + res[2] * res[2] + res[3] * res[3];
#pragma unroll
  for (int off = 32; off; off >>= 1) {
    s1 += __shfl_xor(s1, off, 64);
    s2 += __shfl_xor(s2, off, 64);
  }
  __shared__ float a1[4], a2[4];
  if (lane == 0) { a1[wave] = s1; a2[wave] = s2; }
  __syncthreads();
  float t1 = a1[0] + a1[1] + a1[2] + a1[3];
  float t2 = a2[0] + a2[1] + a2[2] + a2[3];
  float mu = t1 * (1.f / EMB);
  float var = fmaxf(t2 * (1.f / EMB) - mu * mu, 0.f);
  float rstd = 1.f / sqrtf(var + 1e-5f);
  float4 gu = *(const float4*)(gamma + tid * 4);
  float4 bu = *(const float4*)(beta + tid * 4);
  float4 o;
  o.x = (res[0] - mu) * rstd * gu.x + bu.x;
  o.y = (res[1] - mu) * rstd * gu.y + bu.y;
  o.z = (res[2] - mu) * rstd * gu.z + bu.z;
  o.w = (res[3] - mu) * rstd * gu.w + bu.w;
  *(float4*)(out + (size_t)r * EMB + tid * 4) = o;
}

extern "C" void kernel_launch(void* const* d_in, const int* in_sizes, int n_in,
                              void* d_out, int out_size, void* d_ws, size_t ws_size,
                              hipStream_t stream) {
  const float* query = (const float*)d_in[0];
  const float* key   = (const float*)d_in[1];
  const float* value = (const float*)d_in[2];
  const float* Wq = (const float*)d_in[3];
  const float* bq = (const float*)d_in[4];
  const float* Wk = (const float*)d_in[5];
  const float* bk = (const float*)d_in[6];
  const float* Wv = (const float*)d_in[7];
  const float* bv = (const float*)d_in[8];
  const float* Wo = (const float*)d_in[9];
  const float* bo = (const float*)d_in[10];
  const float* cq = (const float*)d_in[11];
  const float* ck = (const float*)d_in[12];
  const float* gamma = (const float*)d_in[13];
  const float* beta  = (const float*)d_in[14];
  float* out = (float*)d_out;   // f32 output (reference dtype)

  const size_t MB_EL = (size_t)MROWS * EMB;   // 4M elements

  // workspace (~33 MB): control block first, then bf16 tensors; proj aliases Qb+Kb.
  int* q_cluster = (int*)d_ws;               // 16 KB
  int* k_cluster = q_cluster + MROWS;        // 16 KB
  int* qcount = k_cluster + MROWS;           // 6 x 64 ints contiguous (one memset)
  int* kcount = qcount + 64;
  int* qoff   = kcount + 64;
  int* koff   = qoff + 64;
  int* qfill  = koff + 64;
  int* kfill  = qfill + 64;
  int* qlist  = kfill + 64;                  // [2][2048]
  int* klist  = qlist + MROWS;               // [2][2048]
  double* Wcq = (double*)(klist + MROWS);    // 256 KB (offset 67072, 16B-aligned)
  double* Wck = Wcq + (size_t)NC * EMB;      // 256 KB
  double* bdq = Wck + (size_t)NC * EMB;
  double* bdk = bdq + NC;
  unsigned short* Qb  = (unsigned short*)(bdk + NC);  // 8 MB bf16, row = seq*2+n
  unsigned short* Kb  = Qb + MB_EL;                   // 8 MB
  unsigned short* Vb  = Kb + MB_EL;                   // 8 MB
  unsigned short* ctx = Vb + MB_EL;                   // 8 MB, row = n*L+l
  float* proj = (float*)Qb;    // 16 MB f32 overlays Qb+Kb (dead after attention)

  hipMemsetAsync(qcount, 0, 6 * 64 * sizeof(int), stream);

  prep_wc_kernel<<<EMB, 256, 0, stream>>>(Wq, bq, cq, Wcq, bdq);
  prep_wc_kernel<<<EMB, 256, 0, stream>>>(Wk, bk, ck, Wck, bdk);

  dim3 gg(EMB / 128, MROWS / 128);
  gemm_bt_mfma<0><<<gg, 256, 0, stream>>>(query, Wq, bq, nullptr, Qb);
  gemm_bt_mfma<0><<<gg, 256, 0, stream>>>(key,   Wk, bk, nullptr, Kb);
  gemm_bt_mfma<0><<<gg, 256, 0, stream>>>(value, Wv, bv, nullptr, Vb);

  assign2_kernel<<<MROWS / 4, 256, 0, stream>>>(query, Wcq, bdq, q_cluster, qcount);
  assign2_kernel<<<MROWS / 4, 256, 0, stream>>>(key,   Wck, bdk, k_cluster, kcount);

  scan_kernel<<<1, 64, 0, stream>>>(qcount, kcount, qoff, koff);
  scatter_kernel<<<(2 * MROWS) / 256, 256, 0, stream>>>(q_cluster, k_cluster, qoff, koff,
                                                        qfill, kfill, qlist, klist);
  attn_bucket<<<dim3(NC, NH, NB), 256, 0, stream>>>(Qb, Kb, Vb, qcount, qoff, qlist,
                                                    kcount, koff, klist, ctx);
  gemm_bt_mfma<1><<<gg, 256, 0, stream>>>(ctx, Wo, bo, proj, nullptr);
  ln_kernel<<<MROWS, 256, 0, stream>>>(proj, query, gamma, beta, out);
}